// Round 7
// baseline (25097.397 us; speedup 1.0000x reference)
//
#include <hip/hip_runtime.h>
#include <cstdint>
#include <cmath>

#define BB 64
#define TT 512
#define NI 256
#define HH 1024
#define NO 512
#define NSTEPS 100
#define KT 64
#define NBLK 256
#define NTHR 512
#define NCTR 64
#define WD2 16384                    // fcW stash base (floats) inside Wall

// ---- persistent device-global state (module-owned; NOT in d_ws) ----
__device__ unsigned g_arr[(NCTR + 1) * 32];  // 64 arrival lines (128B apart)
__device__ __align__(16) float g_hA[HH * BB];
__device__ __align__(16) float g_hB[HH * BB];
__device__ __align__(16) float g_cst[HH * BB];
__device__ __align__(16) float g_dsum[4 * HH];
__device__ __align__(16) float g_logits[NO * BB];
__device__ __align__(16) float g_xt[TT * NI * BB];   // x transposed to [t][k][b]

__device__ __forceinline__ float sigf(float x) { return 1.0f / (1.0f + expf(-x)); }

// ---- agent-coherent access (PROVEN path, rounds 0-3/6: coherent + L2-friendly) ----
__device__ __forceinline__ float2 ldh2(const float* p) {
  unsigned long long u = __hip_atomic_load((const unsigned long long*)p,
                                           __ATOMIC_RELAXED, __HIP_MEMORY_SCOPE_AGENT);
  union { unsigned long long u; float2 f; } c; c.u = u; return c.f;
}
__device__ __forceinline__ float ldc1(const float* p) {
  unsigned u = __hip_atomic_load((const unsigned*)p,
                                 __ATOMIC_RELAXED, __HIP_MEMORY_SCOPE_AGENT);
  union { unsigned u; float f; } c; c.u = u; return c.f;
}
__device__ __forceinline__ void stc1(float* p, float v) {
  union { float f; unsigned u; } c; c.f = v;
  __hip_atomic_store((unsigned*)p, c.u, __ATOMIC_RELAXED, __HIP_MEMORY_SCOPE_AGENT);
}

// release: stc1 stores drained by the vmcnt(0) the compiler emits before
// s_barrier in __syncthreads.
__device__ __forceinline__ void bar_arrive(int blk) {
  __syncthreads();
  if (threadIdx.x == 0) {
    __hip_atomic_fetch_add(&g_arr[(blk & (NCTR - 1)) * 32], 1u,
                           __ATOMIC_RELAXED, __HIP_MEMORY_SCOPE_AGENT);
  }
}

// wave-decoupled wait: wave 0 polls the 64 LLC counters; waves 1..7 spin on an
// LDS flag -> no __syncthreads, no convoy.
__device__ __forceinline__ void bar_wait(unsigned n, unsigned* bf) {
  const int lnw = threadIdx.x & 63;
  if ((threadIdx.x >> 6) == 0) {
    for (;;) {
      unsigned v = __hip_atomic_load(&g_arr[lnw * 32],
                                     __ATOMIC_RELAXED, __HIP_MEMORY_SCOPE_AGENT);
      #pragma unroll
      for (int off = 32; off; off >>= 1) v += __shfl_xor(v, off);
      if (v >= n * NBLK) break;
      __builtin_amdgcn_s_sleep(1);
    }
    if (lnw == 0)
      __hip_atomic_store(bf, n, __ATOMIC_RELEASE, __HIP_MEMORY_SCOPE_WORKGROUP);
  } else {
    while (__hip_atomic_load(bf, __ATOMIC_ACQUIRE, __HIP_MEMORY_SCOPE_WORKGROUP) < n)
      __builtin_amdgcn_s_sleep(2);
  }
}

__global__ void reset_counter() {
  if (threadIdx.x <= NCTR) g_arr[threadIdx.x * 32] = 0u;
}

struct RSlot { float4 a, b; };

// ---- direct-to-register A loads, single 4-slot ring (register diet vs r6) ----
// lane (wv, lrow, lc4): k-rows {8wv+2lrow, +1}, batch cols lc4*4..+3.
#define LDH(R, src, ch) { \
  const float* p_ = (src) + (ch) * 4096 + lanebase; \
  float2 u0_ = ldh2(p_),      u1_ = ldh2(p_ + 2); \
  float2 u2_ = ldh2(p_ + BB), u3_ = ldh2(p_ + BB + 2); \
  (R).a = make_float4(u0_.x, u0_.y, u1_.x, u1_.y); \
  (R).b = make_float4(u2_.x, u2_.y, u3_.x, u3_.y); }

#define LDX(R, src, ch) { \
  const float* p_ = (src) + (ch) * 4096 + lanebase; \
  (R).a = *(const float4*)p_; (R).b = *(const float4*)(p_ + BB); }

// W resident in LDS: Wall[ch*1024 + kl*16 + ((q ^ ((kl>>1)&3))<<2) + pos]
// row r = q*4+pos <-> global row q*HH + blk*4 + pos. Read per (q): 16-lane
// broadcast at quad (q^lrow): conflict-free (VERIFIED r5/r6: 8.8e5 total).
// Only 4-element temp arrays (SROA-safe, r3-proven) -> no scratch.
#define FMA_CH(ch, R) { \
  const float* wp_ = &Wall[(ch) * 1024 + (8 * wv + 2 * lrow) * 16]; \
  _Pragma("unroll") \
  for (int e_ = 0; e_ < 2; ++e_) { \
    const float4 aa_ = e_ ? (R).b : (R).a; \
    const float* wq_ = wp_ + e_ * 16; \
    float av_[4] = {aa_.x, aa_.y, aa_.z, aa_.w}; \
    _Pragma("unroll") \
    for (int q_ = 0; q_ < 4; ++q_) { \
      float4 w4_ = *(const float4*)&wq_[(q_ ^ lrow) << 2]; \
      float wr_[4] = {w4_.x, w4_.y, w4_.z, w4_.w}; \
      _Pragma("unroll") for (int r_ = 0; r_ < 4; ++r_) \
        _Pragma("unroll") for (int c_ = 0; c_ < 4; ++c_) \
          acc[q_ * 4 + r_][c_] = fmaf(wr_[r_], av_[c_], acc[q_ * 4 + r_][c_]); \
    } \
  } }

// D2: register-direct. Lane loads rows {8wv+2lrow, +1}.
#define LOADD2(R, src, ch) \
  { const float* p_ = (src) + (size_t)(((ch) * KT + 8 * wv + 2 * lrow) * BB) + lc4 * 4; \
    float2 u0_ = ldh2(p_),      u1_ = ldh2(p_ + 2); \
    float2 u2_ = ldh2(p_ + BB), u3_ = ldh2(p_ + BB + 2); \
    (R).a = make_float4(u0_.x, u0_.y, u1_.x, u1_.y); \
    (R).b = make_float4(u2_.x, u2_.y, u3_.x, u3_.y); }

#define FMA_D2(R, ch) \
  { const float* wp_ = &Wall[WD2 + (ch) * 256 + wv * 32 + lrow * 4]; \
    float4 w0 = *(const float4*)(wp_); \
    float4 w1 = *(const float4*)(wp_ + 16); \
    float a_[4] = {(R).a.x, (R).a.y, (R).a.z, (R).a.w}; \
    float b2_[4] = {(R).b.x, (R).b.y, (R).b.z, (R).b.w}; \
    float w0_[4] = {w0.x, w0.y, w0.z, w0.w}; \
    float w1_[4] = {w1.x, w1.y, w1.z, w1.w}; \
    _Pragma("unroll") for (int r = 0; r < 4; ++r) \
      _Pragma("unroll") for (int c = 0; c < 4; ++c) { \
        facc[r][c] = fmaf(w0_[r], a_[c], facc[r][c]); \
        facc[r][c] = fmaf(w1_[r], b2_[c], facc[r][c]); \
      } }

#define GPX(q, rt, cb2) Su[(q) * 1156 + (rt) * 68 + (cb2)]

__global__ void __launch_bounds__(NTHR, 2)
seq2seq_kernel(const float* __restrict__ xin,
               const float* __restrict__ eWih, const float* __restrict__ eWhh,
               const float* __restrict__ ebih, const float* __restrict__ ebhh,
               const float* __restrict__ dWih, const float* __restrict__ dWhh,
               const float* __restrict__ dbih, const float* __restrict__ dbhh,
               const float* __restrict__ fcW,  const float* __restrict__ fcb,
               int* __restrict__ out)
{
  // LDS: Su(Gp) 36.1K + Wall 80K + misc 4.3K = 120.4 KiB
  __shared__ __align__(16) float Su[9248];      // Gp partials | D2 Gpd alias
  __shared__ __align__(16) float Wall[20480];   // resident W (swizzled layout)
  __shared__ float avals[8][BB];
  __shared__ int   aidx[8][BB];
  __shared__ float ptok[BB];
  __shared__ unsigned bflag;

  const int tid = threadIdx.x;
  const int blk = blockIdx.x;
  unsigned sync_no = 0;

  const int wv  = tid >> 6;
  const int ln  = tid & 63;
  const int lrow = ln >> 4;                // 0..3: wave-local k row-pair
  const int lc4  = ln & 15;                // batch quad
  const int jj2 = (tid >> 6) & 3;
  const int cb  = tid & 63;
  const int j2  = blk * 4 + jj2;
  const int ktd = 4 * wv + lrow;           // D2 K-group 0..31
  const int lanebase = (8 * wv + 2 * lrow) * BB + lc4 * 4;

  // ---------------- init ----------------
  {
    if (tid == 0) bflag = 0u;
    if (tid < 256) {
      int idx = blk * 256 + tid;
      stc1(&g_hA[idx], 0.0f);           // h: coherent (cross-block)
      g_cst[idx] = 0.0f;                // c: block-private, cached
    }
    int rr = blk * 16 + (tid >> 5);
    int l32 = tid & 31;
    const float* wrp = dWih + (size_t)rr * NO;
    float s = 0.0f;
    for (int k = l32; k < NO; k += 32) s += wrp[k];
    for (int off = 16; off; off >>= 1) s += __shfl_down(s, off, 32);
    if (l32 == 0) stc1(&g_dsum[rr], s);
    // x transpose: coalesced reads, scattered sc1 stores
    for (size_t w = (size_t)blk * NTHR + tid; w < (size_t)TT * NI * BB;
         w += (size_t)NBLK * NTHR) {
      int k = (int)(w & (NI - 1));
      int t = (int)((w >> 8) & (TT - 1));
      int b = (int)(w >> 17);
      stc1(&g_xt[((size_t)t * NI + k) * BB + b], xin[w]);
    }
    // encoder W stash (20 chunks, swizzled): r2 = q*4+pos
    for (int r2 = 0; r2 < 16; ++r2) {
      const int gr = (r2 >> 2) * HH + blk * 4 + (r2 & 3);
      for (int k = tid; k < NI + HH; k += NTHR) {
        const float w = (k < NI) ? eWih[(size_t)gr * NI + k]
                                 : eWhh[(size_t)gr * HH + (k - NI)];
        const int ch = k >> 6, kl = k & 63;
        Wall[ch * 1024 + kl * 16 + (((r2 >> 2) ^ ((kl >> 1) & 3)) << 2) + (r2 & 3)] = w;
      }
    }
  }
  const float be0 = ebih[j2]          + ebhh[j2];
  const float be1 = ebih[HH + j2]     + ebhh[HH + j2];
  const float be2 = ebih[2 * HH + j2] + ebhh[2 * HH + j2];
  const float be3 = ebih[3 * HH + j2] + ebhh[3 * HH + j2];
  bar_arrive(blk); ++sync_no; bar_wait(sync_no, &bflag);

  const float* hc = g_hA;
  float* hn = g_hB;

  RSlot Rs[4];                          // single 4-slot ring (32 VGPRs)
  // prologue: x(t=0) chunks 0..3
  LDX(Rs[0], g_xt, 0);
  LDX(Rs[1], g_xt, 1);
  LDX(Rs[2], g_xt, 2);
  LDX(Rs[3], g_xt, 3);

  // ================ encoder: 512 steps ================
  // W-chunk ch=4..19 pairs with h-chunk (ch-4), held in Rs[ch&3].
  for (int t = 0; t < TT; ++t) {
    float acc[16][4];
    #pragma unroll
    for (int r = 0; r < 16; ++r)
      #pragma unroll
      for (int c = 0; c < 4; ++c) acc[r][c] = 0.0f;

    FMA_CH(0, Rs[0]);
    bar_wait(sync_no, &bflag);           // h(t-1) ready before first h load
    LDH(Rs[0], hc, 0);
    FMA_CH(1, Rs[1]); LDH(Rs[1], hc, 1);
    FMA_CH(2, Rs[2]); LDH(Rs[2], hc, 2);
    FMA_CH(3, Rs[3]); LDH(Rs[3], hc, 3);
    FMA_CH(4, Rs[0]);  LDH(Rs[0], hc, 4);
    FMA_CH(5, Rs[1]);  LDH(Rs[1], hc, 5);
    FMA_CH(6, Rs[2]);  LDH(Rs[2], hc, 6);
    FMA_CH(7, Rs[3]);  LDH(Rs[3], hc, 7);
    FMA_CH(8, Rs[0]);  LDH(Rs[0], hc, 8);
    FMA_CH(9, Rs[1]);  LDH(Rs[1], hc, 9);
    FMA_CH(10, Rs[2]); LDH(Rs[2], hc, 10);
    FMA_CH(11, Rs[3]); LDH(Rs[3], hc, 11);
    FMA_CH(12, Rs[0]); LDH(Rs[0], hc, 12);
    FMA_CH(13, Rs[1]); LDH(Rs[1], hc, 13);
    FMA_CH(14, Rs[2]); LDH(Rs[2], hc, 14);
    FMA_CH(15, Rs[3]); LDH(Rs[3], hc, 15);
    FMA_CH(16, Rs[0]);
    FMA_CH(17, Rs[1]);
    FMA_CH(18, Rs[2]);
    FMA_CH(19, Rs[3]);

    // merge the 4 lrow-groups in-register
    #pragma unroll
    for (int r = 0; r < 16; ++r)
      #pragma unroll
      for (int c = 0; c < 4; ++c) {
        acc[r][c] += __shfl_xor(acc[r][c], 32);
        acc[r][c] += __shfl_xor(acc[r][c], 16);
      }
    __syncthreads();
    if (lrow == 0) {
      #pragma unroll
      for (int r = 0; r < 16; ++r) {
        float4 v = {acc[r][0], acc[r][1], acc[r][2], acc[r][3]};
        *(float4*)&GPX(wv, r, lc4 * 4) = v;
      }
    }
    __syncthreads();
    if (tid < 256) {
      float gsum[4];
      #pragma unroll
      for (int g = 0; g < 4; ++g) {
        const int rt = g * 4 + jj2;
        float ssum = 0.0f;
        #pragma unroll
        for (int q = 0; q < 8; ++q) ssum += GPX(q, rt, cb);
        gsum[g] = ssum;
      }
      float pi = gsum[0] + be0;
      float pf = gsum[1] + be1;
      float pg = gsum[2] + be2;
      float po = gsum[3] + be3;
      float co = g_cst[(size_t)j2 * BB + cb];
      float cn = sigf(pf) * co + sigf(pi) * tanhf(pg);
      float hv = sigf(po) * tanhf(cn);
      g_cst[(size_t)j2 * BB + cb] = cn;
      stc1(&hn[(size_t)j2 * BB + cb], hv);
    }
    // refill ring with next step's x chunks (plain/L2); hides under barrier
    {
      const int tn = (t + 1 < TT) ? t + 1 : t;
      const float* xb = g_xt + (size_t)tn * NI * BB;
      LDX(Rs[0], xb, 0);
      LDX(Rs[1], xb, 1);
      LDX(Rs[2], xb, 2);
      LDX(Rs[3], xb, 3);
    }
    bar_arrive(blk); ++sync_no;
    { float* tmp = (float*)hc; hc = hn; hn = tmp; }
  }
  if (tid < BB) ptok[tid] = 0.0f;
  bar_wait(sync_no, &bflag);             // final encoder h visible

  // D1 s=0 chunks 0..3 prefetch (overlaps Wall refill)
  LDH(Rs[0], hc, 0);
  LDH(Rs[1], hc, 1);
  LDH(Rs[2], hc, 2);
  LDH(Rs[3], hc, 3);
  // ---- decoder W stash: dWhh (chunks 0..15, swizzled) + fcW (blocks 0..127) ----
  for (int r2 = 0; r2 < 16; ++r2) {
    const int gr = (r2 >> 2) * HH + blk * 4 + (r2 & 3);
    for (int k = tid; k < HH; k += NTHR) {
      const int ch = k >> 6, kl = k & 63;
      Wall[ch * 1024 + kl * 16 + (((r2 >> 2) ^ ((kl >> 1) & 3)) << 2) + (r2 & 3)] =
          dWhh[(size_t)gr * HH + k];
    }
  }
  if (blk < 128) {
    for (int k = tid; k < HH; k += NTHR) {
      const int ch = k >> 6, kl = k & 63, wt = kl >> 3, lo = kl & 7;
      const int base = WD2 + ch * 256 + wt * 32 + (lo & 1) * 16 + (lo >> 1) * 4;
      #pragma unroll
      for (int oo = 0; oo < 4; ++oo)
        Wall[base + oo] = fcW[(size_t)(blk * 4 + oo) * HH + k];
    }
  }
  __syncthreads();                       // Wall ready

  // ================ decoder: 100 steps ================
  const float bd0 = dbih[j2]          + dbhh[j2];
  const float bd1 = dbih[HH + j2]     + dbhh[HH + j2];
  const float bd2 = dbih[2 * HH + j2] + dbhh[2 * HH + j2];
  const float bd3 = dbih[3 * HH + j2] + dbhh[3 * HH + j2];
  const float ds0 = g_dsum[j2];
  const float ds1 = g_dsum[HH + j2];
  const float ds2 = g_dsum[2 * HH + j2];
  const float ds3 = g_dsum[3 * HH + j2];

  for (int s = 0; s < NSTEPS; ++s) {
    // ---- D1: LSTM cell, K = HH, 16 chunks (W-chunk == h-chunk) ----
    float acc[16][4];
    #pragma unroll
    for (int r = 0; r < 16; ++r)
      #pragma unroll
      for (int c = 0; c < 4; ++c) acc[r][c] = 0.0f;

    FMA_CH(0, Rs[0]); LDH(Rs[0], hc, 4);
    FMA_CH(1, Rs[1]); LDH(Rs[1], hc, 5);
    FMA_CH(2, Rs[2]); LDH(Rs[2], hc, 6);
    FMA_CH(3, Rs[3]); LDH(Rs[3], hc, 7);
    FMA_CH(4, Rs[0]);  LDH(Rs[0], hc, 8);
    FMA_CH(5, Rs[1]);  LDH(Rs[1], hc, 9);
    FMA_CH(6, Rs[2]);  LDH(Rs[2], hc, 10);
    FMA_CH(7, Rs[3]);  LDH(Rs[3], hc, 11);
    FMA_CH(8, Rs[0]);  LDH(Rs[0], hc, 12);
    FMA_CH(9, Rs[1]);  LDH(Rs[1], hc, 13);
    FMA_CH(10, Rs[2]); LDH(Rs[2], hc, 14);
    FMA_CH(11, Rs[3]); LDH(Rs[3], hc, 15);
    FMA_CH(12, Rs[0]);
    FMA_CH(13, Rs[1]);
    FMA_CH(14, Rs[2]);
    FMA_CH(15, Rs[3]);

    #pragma unroll
    for (int r = 0; r < 16; ++r)
      #pragma unroll
      for (int c = 0; c < 4; ++c) {
        acc[r][c] += __shfl_xor(acc[r][c], 32);
        acc[r][c] += __shfl_xor(acc[r][c], 16);
      }
    __syncthreads();
    if (lrow == 0) {
      #pragma unroll
      for (int r = 0; r < 16; ++r) {
        float4 v = {acc[r][0], acc[r][1], acc[r][2], acc[r][3]};
        *(float4*)&GPX(wv, r, lc4 * 4) = v;
      }
    }
    __syncthreads();
    if (tid < 256) {
      float gsum[4];
      #pragma unroll
      for (int g = 0; g < 4; ++g) {
        const int rt = g * 4 + jj2;
        float ssum = 0.0f;
        #pragma unroll
        for (int q = 0; q < 8; ++q) ssum += GPX(q, rt, cb);
        gsum[g] = ssum;
      }
      float tk = ptok[cb];
      float pi = gsum[0] + bd0 + tk * ds0;
      float pf = gsum[1] + bd1 + tk * ds1;
      float pg = gsum[2] + bd2 + tk * ds2;
      float po = gsum[3] + bd3 + tk * ds3;
      float co = g_cst[(size_t)j2 * BB + cb];
      float cn = sigf(pf) * co + sigf(pi) * tanhf(pg);
      float hv = sigf(po) * tanhf(cn);
      g_cst[(size_t)j2 * BB + cb] = cn;
      stc1(&hn[(size_t)j2 * BB + cb], hv);
    }
    bar_arrive(blk); ++sync_no; bar_wait(sync_no, &bflag);
    { float* tmp = (float*)hc; hc = hn; hn = tmp; }   // hc = new h

    // ---- D2: logits (blocks 0..127), register-direct ----
    if (blk < 128) {
      float facc[4][4];
      #pragma unroll
      for (int r = 0; r < 4; ++r)
        #pragma unroll
        for (int c = 0; c < 4; ++c) facc[r][c] = 0.0f;

      LOADD2(Rs[0], hc, 0); LOADD2(Rs[1], hc, 1);
      LOADD2(Rs[2], hc, 2); LOADD2(Rs[3], hc, 3);
      for (int cb4 = 0; cb4 < 3; ++cb4) {
        const int cc = cb4 * 4;
        FMA_D2(Rs[0], cc);     LOADD2(Rs[0], hc, cc + 4);
        FMA_D2(Rs[1], cc + 1); LOADD2(Rs[1], hc, cc + 5);
        FMA_D2(Rs[2], cc + 2); LOADD2(Rs[2], hc, cc + 6);
        FMA_D2(Rs[3], cc + 3); LOADD2(Rs[3], hc, cc + 7);
      }
      FMA_D2(Rs[0], 12); FMA_D2(Rs[1], 13); FMA_D2(Rs[2], 14); FMA_D2(Rs[3], 15);

      #pragma unroll
      for (int r = 0; r < 4; ++r) {
        float4 v = {facc[r][0], facc[r][1], facc[r][2], facc[r][3]};
        *(float4*)&Su[ktd * 272 + r * 68 + lc4 * 4] = v;
      }
      __syncthreads();
      if (tid < 256) {
        const int oo = tid >> 6, ob = tid & 63;
        float ssum = 0.0f;
        #pragma unroll
        for (int q = 0; q < 32; ++q) ssum += Su[q * 272 + oo * 68 + ob];
        const int o = blk * 4 + oo;
        stc1(&g_logits[(size_t)o * BB + ob], ssum + fcb[o]);
      }
    }
    // prefetch next D1 chunks 0..3 (hc unchanged through argmax)
    LDH(Rs[0], hc, 0);
    LDH(Rs[1], hc, 1);
    LDH(Rs[2], hc, 2);
    LDH(Rs[3], hc, 3);
    bar_arrive(blk); ++sync_no; bar_wait(sync_no, &bflag);

    // ---- argmax (redundant per block; first-index tie-break) ----
    {
      const int q = tid >> 6, b = tid & 63;
      float bv = -3.402823466e38f; int bo = 0;
      #pragma unroll
      for (int g = 0; g < 4; ++g) {
        float lv[16];
        #pragma unroll
        for (int i = 0; i < 16; ++i)
          lv[i] = ldc1(&g_logits[(size_t)(q * 64 + g * 16 + i) * BB + b]);
        #pragma unroll
        for (int i = 0; i < 16; ++i)
          if (lv[i] > bv) { bv = lv[i]; bo = q * 64 + g * 16 + i; }
      }
      avals[q][b] = bv; aidx[q][b] = bo;
    }
    __syncthreads();
    if (tid < BB) {
      float bv = avals[0][tid]; int bo = aidx[0][tid];
      #pragma unroll
      for (int q = 1; q < 8; ++q)
        if (avals[q][tid] > bv) { bv = avals[q][tid]; bo = aidx[q][tid]; }
      ptok[tid] = (float)bo;
      if (blk == 0) out[(size_t)tid * NSTEPS + s] = bo;
    }
    __syncthreads();
  }
}

extern "C" void kernel_launch(void* const* d_in, const int* in_sizes, int n_in,
                              void* d_out, int out_size, void* d_ws, size_t ws_size,
                              hipStream_t stream) {
  (void)in_sizes; (void)n_in; (void)out_size; (void)d_ws; (void)ws_size;
  const float* xin  = (const float*)d_in[0];
  const float* eWih = (const float*)d_in[1];
  const float* eWhh = (const float*)d_in[2];
  const float* ebih = (const float*)d_in[3];
  const float* ebhh = (const float*)d_in[4];
  const float* dWih = (const float*)d_in[5];
  const float* dWhh = (const float*)d_in[6];
  const float* dbih = (const float*)d_in[7];
  const float* dbhh = (const float*)d_in[8];
  const float* fcW  = (const float*)d_in[9];
  const float* fcb  = (const float*)d_in[10];
  int* out = (int*)d_out;

  reset_counter<<<1, 128, 0, stream>>>();
  seq2seq_kernel<<<NBLK, NTHR, 0, stream>>>(
      xin, eWih, eWhh, ebih, ebhh, dWih, dWhh, dbih, dbhh, fcW, fcb, out);
}

// Round 8
// 13272.670 us; speedup vs baseline: 1.8909x; 1.8909x over previous
//
#include <hip/hip_runtime.h>
#include <cstdint>
#include <cmath>

#define BB 64
#define TT 512
#define NI 256
#define HH 1024
#define NO 512
#define NSTEPS 100
#define KT 64
#define NBLK 256
#define NTHR 512
#define NCTR 64
#define WD2 16384                    // fcW stash base (floats) inside Wall

// ---- persistent device-global state (module-owned; NOT in d_ws) ----
__device__ unsigned g_arr[(NCTR + 1) * 32];  // 64 arrival lines (128B apart)
__device__ __align__(16) float g_hA[HH * BB];
__device__ __align__(16) float g_hB[HH * BB];
__device__ __align__(16) float g_cst[HH * BB];
__device__ __align__(16) float g_dsum[4 * HH];
__device__ __align__(16) float g_logits[NO * BB];
__device__ __align__(16) float g_xt[TT * NI * BB];   // x transposed to [t][k][b]

__device__ __forceinline__ float sigf(float x) { return 1.0f / (1.0f + expf(-x)); }

// ---- agent-coherent (sc1) access via intrinsics ----
__device__ __forceinline__ float2 ldh2(const float* p) {
  unsigned long long u = __hip_atomic_load((const unsigned long long*)p,
                                           __ATOMIC_RELAXED, __HIP_MEMORY_SCOPE_AGENT);
  union { unsigned long long u; float2 f; } c; c.u = u; return c.f;
}
__device__ __forceinline__ float ldc1(const float* p) {
  unsigned u = __hip_atomic_load((const unsigned*)p,
                                 __ATOMIC_RELAXED, __HIP_MEMORY_SCOPE_AGENT);
  union { unsigned u; float f; } c; c.u = u; return c.f;
}
__device__ __forceinline__ void stc1(float* p, float v) {
  union { float f; unsigned u; } c; c.f = v;
  __hip_atomic_store((unsigned*)p, c.u, __ATOMIC_RELAXED, __HIP_MEMORY_SCOPE_AGENT);
}

// release: sc1 stores drained by the vmcnt(0) before s_barrier in bar_arrive.
__device__ __forceinline__ void bar_arrive(int blk) {
  __syncthreads();
  if (threadIdx.x == 0) {
    __hip_atomic_fetch_add(&g_arr[(blk & (NCTR - 1)) * 32], 1u,
                           __ATOMIC_RELAXED, __HIP_MEMORY_SCOPE_AGENT);
  }
}

// wave-decoupled wait: wave 0 polls the 64 LLC counters; waves 1..7 spin on an
// LDS flag (workgroup acquire/release) -> no __syncthreads, no convoy.
__device__ __forceinline__ void bar_wait(unsigned n, unsigned* bf) {
  const int ln = threadIdx.x & 63;
  if ((threadIdx.x >> 6) == 0) {
    for (;;) {
      unsigned v = __hip_atomic_load(&g_arr[ln * 32],
                                     __ATOMIC_RELAXED, __HIP_MEMORY_SCOPE_AGENT);
      #pragma unroll
      for (int off = 32; off; off >>= 1) v += __shfl_xor(v, off);
      if (v >= n * NBLK) break;
      __builtin_amdgcn_s_sleep(1);
    }
    if (ln == 0)
      __hip_atomic_store(bf, n, __ATOMIC_RELEASE, __HIP_MEMORY_SCOPE_WORKGROUP);
  } else {
    while (__hip_atomic_load(bf, __ATOMIC_ACQUIRE, __HIP_MEMORY_SCOPE_WORKGROUP) < n)
      __builtin_amdgcn_s_sleep(2);
  }
}

__global__ void reset_counter() {
  if (threadIdx.x <= NCTR) g_arr[threadIdx.x * 32] = 0u;
}

struct RSlot { float4 a, b; };

// ---- per-wave A staging: wave wv owns K-rows 8wv..8wv+7 of each chunk ----
// lane ln: rows lrow and lrow+4, 16B col lc4. LDS layout: 8 rows x 64 floats,
// 16B slot XOR-swizzled by (row>>1).
#define LOADC_X(R, src) \
  { const float* p_ = (src) + (size_t)((8 * wv + lrow) * BB) + lc4 * 4; \
    (R).a = *(const float4*)p_; \
    (R).b = *(const float4*)(p_ + 4 * BB); }

#define LOADC_H(R, src) \
  { const float* p_ = (src) + (size_t)((8 * wv + lrow) * BB) + lc4 * 4; \
    float2 u0_ = ldh2(p_),        u1_ = ldh2(p_ + 2); \
    float2 u2_ = ldh2(p_ + 4*BB), u3_ = ldh2(p_ + 4*BB + 2); \
    (R).a = make_float4(u0_.x, u0_.y, u1_.x, u1_.y); \
    (R).b = make_float4(u2_.x, u2_.y, u3_.x, u3_.y); }

#define STOREC(bufi, R) \
  { float* b_ = &Su[AsW + (bufi) * 512]; \
    *(float4*)&b_[st0] = (R).a; \
    *(float4*)&b_[st1] = (R).b; }

#define FMA_CHUNK(bufi, ch) \
  { const float* ab_ = &Su[AsW + (bufi) * 512 + row2 * 64]; \
    const float* wp_ = &Wall[(ch) * 1024 + wb]; \
    _Pragma("unroll") \
    for (int kk2 = 0; kk2 < 2; ++kk2) { \
      float4 a0 = *(const float4*)(ab_ + kk2 * 64 + a0c); \
      float4 a1 = *(const float4*)(ab_ + kk2 * 64 + a1c); \
      float4 w0 = *(const float4*)(wp_ + kk2 * 64); \
      float4 w1 = *(const float4*)(wp_ + kk2 * 64 + 4); \
      float av_[8] = {a0.x, a0.y, a0.z, a0.w, a1.x, a1.y, a1.z, a1.w}; \
      float wv_[8] = {w0.x, w0.y, w0.z, w0.w, w1.x, w1.y, w1.z, w1.w}; \
      _Pragma("unroll") for (int r = 0; r < 8; ++r) \
        _Pragma("unroll") for (int c = 0; c < 8; ++c) \
          acc[r][c] = fmaf(wv_[r], av_[c], acc[r][c]); \
    } }

// D2: register-direct (no LDS). Lane loads exactly rows {2*lrow, 2*lrow+1}.
#define LOADD2(R, src, ch) \
  { const float* p_ = (src) + (size_t)(((ch) * KT + 8 * wv + 2 * lrow) * BB) + lc4 * 4; \
    float2 u0_ = ldh2(p_),      u1_ = ldh2(p_ + 2); \
    float2 u2_ = ldh2(p_ + BB), u3_ = ldh2(p_ + BB + 2); \
    (R).a = make_float4(u0_.x, u0_.y, u1_.x, u1_.y); \
    (R).b = make_float4(u2_.x, u2_.y, u3_.x, u3_.y); }

#define FMA_D2(R, ch) \
  { const float* wp_ = &Wall[WD2 + (ch) * 256 + wv * 32 + lrow * 4]; \
    float4 w0 = *(const float4*)(wp_); \
    float4 w1 = *(const float4*)(wp_ + 16); \
    float a_[4] = {(R).a.x, (R).a.y, (R).a.z, (R).a.w}; \
    float b2_[4] = {(R).b.x, (R).b.y, (R).b.z, (R).b.w}; \
    float w0_[4] = {w0.x, w0.y, w0.z, w0.w}; \
    float w1_[4] = {w1.x, w1.y, w1.z, w1.w}; \
    _Pragma("unroll") for (int r = 0; r < 4; ++r) \
      _Pragma("unroll") for (int c = 0; c < 4; ++c) { \
        facc[r][c] = fmaf(w0_[r], a_[c], facc[r][c]); \
        facc[r][c] = fmaf(w1_[r], b2_[c], facc[r][c]); \
      } }

#define GPX(q, rt, cb2) Su[(q) * 1156 + (rt) * 68 + (cb2)]

__global__ void __launch_bounds__(NTHR, 1)
seq2seq_kernel(const float* __restrict__ xin,
               const float* __restrict__ eWih, const float* __restrict__ eWhh,
               const float* __restrict__ ebih, const float* __restrict__ ebhh,
               const float* __restrict__ dWih, const float* __restrict__ dWhh,
               const float* __restrict__ dbih, const float* __restrict__ dbhh,
               const float* __restrict__ fcW,  const float* __restrict__ fcb,
               int* __restrict__ out)
{
  // LDS: Su (As 8x1024 U Gp 9248) 36.1K + Wall 80K + misc 4.3K = 120.4 KiB
  __shared__ __align__(16) float Su[9248];      // union: per-wave As | Gp partials
  __shared__ __align__(16) float Wall[20480];   // resident W (per-wave layout)
  __shared__ float avals[8][BB];
  __shared__ int   aidx[8][BB];
  __shared__ float ptok[BB];
  __shared__ unsigned bflag;

  const int tid = threadIdx.x;
  const int blk = blockIdx.x;
  unsigned sync_no = 0;

  const int wv  = tid >> 6;
  const int ln  = tid & 63;
  const int hi  = ln >> 5;
  const int l5  = ln & 31;
  const int jl  = ((l5 >> 4) << 1) | hi;   // 0..3: wave-local K row-pair
  const int rg  = (l5 >> 3) & 1;
  const int cg  = l5 & 7;
  const int lrow = ln >> 4;                // 0..3 staging row
  const int lc4  = ln & 15;                // 16B col
  const int jj2 = (tid >> 6) & 3;
  const int cb  = tid & 63;
  const int j2  = blk * 4 + jj2;
  const int ktd = 4 * wv + lrow;           // D2 K-group 0..31
  const int AsW = wv * 1024;
  const int st0 = lrow * 64 + ((lc4 ^ (lrow >> 1)) << 2);
  const int st1 = (lrow + 4) * 64 + ((lc4 ^ ((lrow >> 1) + 2)) << 2);
  const int row2 = 2 * jl;
  const int a0c = (((cg << 1) ^ jl) << 2);
  const int a1c = ((((cg << 1) | 1) ^ jl) << 2);
  const int wb  = wv * 128 + (((jl << 1) | rg) << 3);

  // ---------------- init ----------------
  {
    if (tid == 0) bflag = 0u;
    if (tid < 256) {
      int idx = blk * 256 + tid;
      stc1(&g_hA[idx], 0.0f);           // h: coherent (cross-block)
      g_cst[idx] = 0.0f;                // c: block-private, cached
    }
    int rr = blk * 16 + (tid >> 5);
    int l32 = tid & 31;
    const float* wrp = dWih + (size_t)rr * NO;
    float s = 0.0f;
    for (int k = l32; k < NO; k += 32) s += wrp[k];
    for (int off = 16; off; off >>= 1) s += __shfl_down(s, off, 32);
    if (l32 == 0) stc1(&g_dsum[rr], s);
    // x transpose: coalesced reads, scattered sc1 stores
    for (size_t w = (size_t)blk * NTHR + tid; w < (size_t)TT * NI * BB;
         w += (size_t)NBLK * NTHR) {
      int k = (int)(w & (NI - 1));
      int t = (int)((w >> 8) & (TT - 1));
      int b = (int)(w >> 17);
      stc1(&g_xt[((size_t)t * NI + k) * BB + b], xin[w]);
    }
    // encoder W stash: per-wave layout [ch][wv][kk2][(jl<<1)|rg][half][4]
    for (int c = 0; c < 16; ++c) {
      const int gr = (c >> 2) * HH + blk * 4 + (c & 3);
      const int rgc = c >> 3, rc = c & 7, half = rc >> 2, q = rc & 3;
      for (int k = tid; k < NI + HH; k += NTHR) {
        const float w = (k < NI) ? eWih[(size_t)gr * NI + k]
                                 : eWhh[(size_t)gr * HH + (k - NI)];
        const int ch = k >> 6, kl = k & 63, wt = kl >> 3, lo = kl & 7;
        Wall[ch * 1024 + wt * 128 + (lo & 1) * 64 +
             ((((lo >> 1) << 1) | rgc) << 3) + half * 4 + q] = w;
      }
    }
  }
  const float be0 = ebih[j2]          + ebhh[j2];
  const float be1 = ebih[HH + j2]     + ebhh[HH + j2];
  const float be2 = ebih[2 * HH + j2] + ebhh[2 * HH + j2];
  const float be3 = ebih[3 * HH + j2] + ebhh[3 * HH + j2];
  bar_arrive(blk); ++sync_no; bar_wait(sync_no, &bflag);

  const float* hc = g_hA;
  float* hn = g_hB;

  RSlot Rs[4];
  // prologue: x(t=0) chunks 0,1,2
  LOADC_X(Rs[0], g_xt);
  LOADC_X(Rs[1], g_xt + (size_t)KT * BB);
  LOADC_X(Rs[2], g_xt + (size_t)2 * KT * BB);

  // ================ encoder: 512 steps, wave-private pipeline ================
  for (int t = 0; t < TT; ++t) {
    float acc[8][8];
    #pragma unroll
    for (int r = 0; r < 8; ++r)
      #pragma unroll
      for (int c = 0; c < 8; ++c) acc[r][c] = 0.0f;

    STOREC(0, Rs[0]);                                       // chunk 0
    // cc=0
    STOREC(1, Rs[1]);
    LOADC_X(Rs[3], g_xt + ((size_t)t * NI + 3 * KT) * BB);
    FMA_CHUNK(0, 0);
    // cc=1 : h(t-1) becomes safe to read here
    bar_wait(sync_no, &bflag);
    STOREC(0, Rs[2]);
    LOADC_H(Rs[0], hc);
    LOADC_H(Rs[1], hc + (size_t)KT * BB);
    FMA_CHUNK(1, 1);
    // cc=2
    STOREC(1, Rs[3]);
    LOADC_H(Rs[2], hc + (size_t)2 * KT * BB);
    FMA_CHUNK(0, 2);
    // cc=3
    STOREC(0, Rs[0]);                                       // chunk 4 (h0)
    LOADC_H(Rs[3], hc + (size_t)3 * KT * BB);
    FMA_CHUNK(1, 3);
    // cc=4..15
    for (int cb4 = 0; cb4 < 3; ++cb4) {
      const int cc = 4 + cb4 * 4;
      STOREC(1, Rs[1]); LOADC_H(Rs[0], hc + (size_t)(cc    ) * KT * BB); FMA_CHUNK(0, cc);
      STOREC(0, Rs[2]); LOADC_H(Rs[1], hc + (size_t)(cc + 1) * KT * BB); FMA_CHUNK(1, cc + 1);
      STOREC(1, Rs[3]); LOADC_H(Rs[2], hc + (size_t)(cc + 2) * KT * BB); FMA_CHUNK(0, cc + 2);
      STOREC(0, Rs[0]); LOADC_H(Rs[3], hc + (size_t)(cc + 3) * KT * BB); FMA_CHUNK(1, cc + 3);
    }
    // cc=16..19 (wrap loads to next step's x chunks)
    {
      const int tn = (t + 1 < TT) ? t + 1 : t;
      STOREC(1, Rs[1]); LOADC_X(Rs[0], g_xt + (size_t)tn * NI * BB);            FMA_CHUNK(0, 16);
      STOREC(0, Rs[2]); LOADC_X(Rs[1], g_xt + ((size_t)tn * NI + KT) * BB);     FMA_CHUNK(1, 17);
      STOREC(1, Rs[3]); LOADC_X(Rs[2], g_xt + ((size_t)tn * NI + 2 * KT) * BB); FMA_CHUNK(0, 18);
      FMA_CHUNK(1, 19);
    }
    // merge the 4 wave-local K-groups in-register
    #pragma unroll
    for (int r = 0; r < 8; ++r)
      #pragma unroll
      for (int c = 0; c < 8; ++c) {
        acc[r][c] += __shfl_xor(acc[r][c], 32);
        acc[r][c] += __shfl_xor(acc[r][c], 16);
      }
    __syncthreads();                     // all As reads done -> Gp may overwrite
    if (ln < 16) {
      #pragma unroll
      for (int r = 0; r < 8; ++r) {
        float4 v0 = {acc[r][0], acc[r][1], acc[r][2], acc[r][3]};
        float4 v1 = {acc[r][4], acc[r][5], acc[r][6], acc[r][7]};
        *(float4*)&GPX(wv, rg * 8 + r, cg * 8)     = v0;
        *(float4*)&GPX(wv, rg * 8 + r, cg * 8 + 4) = v1;
      }
    }
    __syncthreads();
    if (tid < 256) {
      float gsum[4];
      #pragma unroll
      for (int g = 0; g < 4; ++g) {
        const int rt = g * 4 + jj2;
        float ssum = 0.0f;
        #pragma unroll
        for (int q = 0; q < 8; ++q) ssum += GPX(q, rt, cb);
        gsum[g] = ssum;
      }
      float pi = gsum[0] + be0;
      float pf = gsum[1] + be1;
      float pg = gsum[2] + be2;
      float po = gsum[3] + be3;
      float co = g_cst[(size_t)j2 * BB + cb];
      float cn = sigf(pf) * co + sigf(pi) * tanhf(pg);
      float hv = sigf(po) * tanhf(cn);
      g_cst[(size_t)j2 * BB + cb] = cn;
      stc1(&hn[(size_t)j2 * BB + cb], hv);
    }
    bar_arrive(blk); ++sync_no;
    { float* tmp = (float*)hc; hc = hn; hn = tmp; }
  }
  if (tid < BB) ptok[tid] = 0.0f;
  bar_wait(sync_no, &bflag);             // final encoder h visible

  // ---- decoder W stash: dWhh (chunks 0..15) + fcW (blocks 0..127) ----
  // (encoder FMAs all completed before the last bar_arrive's __syncthreads)
  LOADC_H(Rs[0], hc);                    // D1 s=0 prefetch, overlaps stash fill
  LOADC_H(Rs[1], hc + (size_t)KT * BB);
  LOADC_H(Rs[2], hc + (size_t)2 * KT * BB);
  LOADC_H(Rs[3], hc + (size_t)3 * KT * BB);
  for (int c = 0; c < 16; ++c) {
    const int gr = (c >> 2) * HH + blk * 4 + (c & 3);
    const int rgc = c >> 3, rc = c & 7, half = rc >> 2, q = rc & 3;
    for (int k = tid; k < HH; k += NTHR) {
      const float w = dWhh[(size_t)gr * HH + k];
      const int ch = k >> 6, kl = k & 63, wt = kl >> 3, lo = kl & 7;
      Wall[ch * 1024 + wt * 128 + (lo & 1) * 64 +
           ((((lo >> 1) << 1) | rgc) << 3) + half * 4 + q] = w;
    }
  }
  if (blk < 128) {
    for (int k = tid; k < HH; k += NTHR) {
      const int ch = k >> 6, kl = k & 63, wt = kl >> 3, lo = kl & 7;
      const int base = WD2 + ch * 256 + wt * 32 + (lo & 1) * 16 + (lo >> 1) * 4;
      #pragma unroll
      for (int oo = 0; oo < 4; ++oo)
        Wall[base + oo] = fcW[(size_t)(blk * 4 + oo) * HH + k];
    }
  }
  __syncthreads();                       // Wall ready for all waves

  // ================ decoder: 100 steps ================
  const float bd0 = dbih[j2]          + dbhh[j2];
  const float bd1 = dbih[HH + j2]     + dbhh[HH + j2];
  const float bd2 = dbih[2 * HH + j2] + dbhh[2 * HH + j2];
  const float bd3 = dbih[3 * HH + j2] + dbhh[3 * HH + j2];
  const float ds0 = g_dsum[j2];
  const float ds1 = g_dsum[HH + j2];
  const float ds2 = g_dsum[2 * HH + j2];
  const float ds3 = g_dsum[3 * HH + j2];

  for (int s = 0; s < NSTEPS; ++s) {
    // ---- D1: LSTM cell, K = HH, 16 chunks, wave-private pipeline ----
    float acc[8][8];
    #pragma unroll
    for (int r = 0; r < 8; ++r)
      #pragma unroll
      for (int c = 0; c < 8; ++c) acc[r][c] = 0.0f;

    STOREC(0, Rs[0]);                                       // chunk 0
    STOREC(1, Rs[1]); LOADC_H(Rs[0], hc + (size_t)4 * KT * BB); FMA_CHUNK(0, 0);
    STOREC(0, Rs[2]); LOADC_H(Rs[1], hc + (size_t)5 * KT * BB); FMA_CHUNK(1, 1);
    STOREC(1, Rs[3]); LOADC_H(Rs[2], hc + (size_t)6 * KT * BB); FMA_CHUNK(0, 2);
    STOREC(0, Rs[0]); LOADC_H(Rs[3], hc + (size_t)7 * KT * BB); FMA_CHUNK(1, 3);
    for (int cb4 = 0; cb4 < 2; ++cb4) {
      const int cc = 4 + cb4 * 4;
      STOREC(1, Rs[1]); LOADC_H(Rs[0], hc + (size_t)(cc + 4) * KT * BB); FMA_CHUNK(0, cc);
      STOREC(0, Rs[2]); LOADC_H(Rs[1], hc + (size_t)(cc + 5) * KT * BB); FMA_CHUNK(1, cc + 1);
      STOREC(1, Rs[3]); LOADC_H(Rs[2], hc + (size_t)(cc + 6) * KT * BB); FMA_CHUNK(0, cc + 2);
      STOREC(0, Rs[0]); LOADC_H(Rs[3], hc + (size_t)(cc + 7) * KT * BB); FMA_CHUNK(1, cc + 3);
    }
    STOREC(1, Rs[1]); FMA_CHUNK(0, 12);
    STOREC(0, Rs[2]); FMA_CHUNK(1, 13);
    STOREC(1, Rs[3]); FMA_CHUNK(0, 14);
    FMA_CHUNK(1, 15);

    #pragma unroll
    for (int r = 0; r < 8; ++r)
      #pragma unroll
      for (int c = 0; c < 8; ++c) {
        acc[r][c] += __shfl_xor(acc[r][c], 32);
        acc[r][c] += __shfl_xor(acc[r][c], 16);
      }
    __syncthreads();
    if (ln < 16) {
      #pragma unroll
      for (int r = 0; r < 8; ++r) {
        float4 v0 = {acc[r][0], acc[r][1], acc[r][2], acc[r][3]};
        float4 v1 = {acc[r][4], acc[r][5], acc[r][6], acc[r][7]};
        *(float4*)&GPX(wv, rg * 8 + r, cg * 8)     = v0;
        *(float4*)&GPX(wv, rg * 8 + r, cg * 8 + 4) = v1;
      }
    }
    __syncthreads();
    if (tid < 256) {
      float gsum[4];
      #pragma unroll
      for (int g = 0; g < 4; ++g) {
        const int rt = g * 4 + jj2;
        float ssum = 0.0f;
        #pragma unroll
        for (int q = 0; q < 8; ++q) ssum += GPX(q, rt, cb);
        gsum[g] = ssum;
      }
      float tk = ptok[cb];
      float pi = gsum[0] + bd0 + tk * ds0;
      float pf = gsum[1] + bd1 + tk * ds1;
      float pg = gsum[2] + bd2 + tk * ds2;
      float po = gsum[3] + bd3 + tk * ds3;
      float co = g_cst[(size_t)j2 * BB + cb];
      float cn = sigf(pf) * co + sigf(pi) * tanhf(pg);
      float hv = sigf(po) * tanhf(cn);
      g_cst[(size_t)j2 * BB + cb] = cn;
      stc1(&hn[(size_t)j2 * BB + cb], hv);
    }
    bar_arrive(blk); ++sync_no; bar_wait(sync_no, &bflag);
    { float* tmp = (float*)hc; hc = hn; hn = tmp; }   // hc = new h

    // ---- D2: logits (blocks 0..127), register-direct, no LDS staging ----
    if (blk < 128) {
      float facc[4][4];
      #pragma unroll
      for (int r = 0; r < 4; ++r)
        #pragma unroll
        for (int c = 0; c < 4; ++c) facc[r][c] = 0.0f;

      LOADD2(Rs[0], hc, 0); LOADD2(Rs[1], hc, 1);
      LOADD2(Rs[2], hc, 2); LOADD2(Rs[3], hc, 3);
      for (int cb4 = 0; cb4 < 3; ++cb4) {
        const int cc = cb4 * 4;
        FMA_D2(Rs[0], cc);     LOADD2(Rs[0], hc, cc + 4);
        FMA_D2(Rs[1], cc + 1); LOADD2(Rs[1], hc, cc + 5);
        FMA_D2(Rs[2], cc + 2); LOADD2(Rs[2], hc, cc + 6);
        FMA_D2(Rs[3], cc + 3); LOADD2(Rs[3], hc, cc + 7);
      }
      FMA_D2(Rs[0], 12); FMA_D2(Rs[1], 13); FMA_D2(Rs[2], 14); FMA_D2(Rs[3], 15);

      // K-split partials (wave-private rows of Gpd alias Su; As is dead)
      #pragma unroll
      for (int r = 0; r < 4; ++r) {
        float4 v = {facc[r][0], facc[r][1], facc[r][2], facc[r][3]};
        *(float4*)&Su[ktd * 272 + r * 68 + lc4 * 4] = v;
      }
      __syncthreads();
      if (tid < 256) {
        const int oo = tid >> 6, ob = tid & 63;
        float ssum = 0.0f;
        #pragma unroll
        for (int q = 0; q < 32; ++q) ssum += Su[q * 272 + oo * 68 + ob];
        const int o = blk * 4 + oo;
        stc1(&g_logits[(size_t)o * BB + ob], ssum + fcb[o]);
      }
    }
    // prefetch next D1 chunks 0..3 (hc unchanged through argmax)
    LOADC_H(Rs[0], hc);
    LOADC_H(Rs[1], hc + (size_t)KT * BB);
    LOADC_H(Rs[2], hc + (size_t)2 * KT * BB);
    LOADC_H(Rs[3], hc + (size_t)3 * KT * BB);
    bar_arrive(blk); ++sync_no; bar_wait(sync_no, &bflag);

    // ---- argmax (redundant per block; first-index tie-break) ----
    {
      const int q = tid >> 6, b = tid & 63;
      float bv = -3.402823466e38f; int bo = 0;
      #pragma unroll
      for (int g = 0; g < 4; ++g) {
        float lv[16];
        #pragma unroll
        for (int i = 0; i < 16; ++i)
          lv[i] = ldc1(&g_logits[(size_t)(q * 64 + g * 16 + i) * BB + b]);
        #pragma unroll
        for (int i = 0; i < 16; ++i)
          if (lv[i] > bv) { bv = lv[i]; bo = q * 64 + g * 16 + i; }
      }
      avals[q][b] = bv; aidx[q][b] = bo;
    }
    __syncthreads();
    if (tid < BB) {
      float bv = avals[0][tid]; int bo = aidx[0][tid];
      #pragma unroll
      for (int q = 1; q < 8; ++q)
        if (avals[q][tid] > bv) { bv = avals[q][tid]; bo = aidx[q][tid]; }
      ptok[tid] = (float)bo;
      if (blk == 0) out[(size_t)tid * NSTEPS + s] = bo;
    }
    __syncthreads();
  }
}

extern "C" void kernel_launch(void* const* d_in, const int* in_sizes, int n_in,
                              void* d_out, int out_size, void* d_ws, size_t ws_size,
                              hipStream_t stream) {
  (void)in_sizes; (void)n_in; (void)out_size; (void)d_ws; (void)ws_size;
  const float* xin  = (const float*)d_in[0];
  const float* eWih = (const float*)d_in[1];
  const float* eWhh = (const float*)d_in[2];
  const float* ebih = (const float*)d_in[3];
  const float* ebhh = (const float*)d_in[4];
  const float* dWih = (const float*)d_in[5];
  const float* dWhh = (const float*)d_in[6];
  const float* dbih = (const float*)d_in[7];
  const float* dbhh = (const float*)d_in[8];
  const float* fcW  = (const float*)d_in[9];
  const float* fcb  = (const float*)d_in[10];
  int* out = (int*)d_out;

  reset_counter<<<1, 128, 0, stream>>>();
  seq2seq_kernel<<<NBLK, NTHR, 0, stream>>>(
      xin, eWih, eWhh, ebih, ebhh, dWih, dWhh, dbih, dbhh, fcW, fcb, out);
}